// Round 1
// baseline (441.471 us; speedup 1.0000x reference)
//
#include <hip/hip_runtime.h>
#include <hip/hip_bf16.h>
#include <cstdint>

// Problem constants
#define B_ 4
#define N_ 2048
#define C_ 768
#define H_ 12
#define D_ 64
// SCALE = D^-0.5 = 0.125

typedef __bf16 bf16x8 __attribute__((ext_vector_type(8)));
typedef float f32x4 __attribute__((ext_vector_type(4)));

// RNE float -> bf16 bits (branchless; inputs are finite)
__device__ __forceinline__ unsigned short f2bs(float x) {
  unsigned u = __builtin_bit_cast(unsigned, x);
  unsigned r = (u + 0x7fffu + ((u >> 16) & 1u)) >> 16;
  return (unsigned short)r;
}

__device__ __forceinline__ bf16x8 ldb8(const unsigned short* p) {
  return __builtin_bit_cast(bf16x8, *(const uint4*)p);
}

__device__ __forceinline__ f32x4 mfma16(bf16x8 a, bf16x8 b, f32x4 c) {
  return __builtin_amdgcn_mfma_f32_16x16x32_bf16(a, b, c, 0, 0, 0);
}

// ---------------- weight conversion: 4 x (768x768) f32 -> bf16 ----------------
__global__ void convw_kernel(const float* __restrict__ s0, const float* __restrict__ s1,
                             const float* __restrict__ s2, const float* __restrict__ s3,
                             unsigned short* __restrict__ d0, unsigned short* __restrict__ d1,
                             unsigned short* __restrict__ d2, unsigned short* __restrict__ d3) {
  const float* s; unsigned short* d;
  switch (blockIdx.y) {
    case 0: s = s0; d = d0; break;
    case 1: s = s1; d = d1; break;
    case 2: s = s2; d = d2; break;
    default: s = s3; d = d3; break;
  }
  int i = (blockIdx.x * 256 + threadIdx.x) * 4;   // grid.x=576 -> covers 589824 exactly
  float4 v = *(const float4*)(s + i);
  ushort4 h;
  h.x = f2bs(v.x); h.y = f2bs(v.y); h.z = f2bs(v.z); h.w = f2bs(v.w);
  *(ushort4*)(d + i) = h;
}

// ---------------- uc[b,n] = mean over C of x_u ----------------
__global__ void uc_kernel(const float* __restrict__ xu, float* __restrict__ uc) {
  int w = threadIdx.x >> 6, lane = threadIdx.x & 63;
  int row = blockIdx.x * 4 + w;                   // grid 2048 -> 8192 rows
  const float* p = xu + (size_t)row * C_;
  float s = 0.f;
#pragma unroll
  for (int i = 0; i < 3; ++i) {                   // 192 float4 per row = 3 per lane
    float4 v = *(const float4*)(p + (i * 64 + lane) * 4);
    s += v.x + v.y + v.z + v.w;
  }
#pragma unroll
  for (int off = 1; off < 64; off <<= 1) s += __shfl_xor(s, off);
  if (lane == 0) uc[row] = s * (1.f / 768.f);
}

// ---------------- NT GEMM: C[M=8192, 768] = A[M,768] @ W[768,768]^T ----------------
// AMODE 0: A is f32 (convert during staging). AMODE 1: A is bf16.
// EPI 0: *= SCALE*uc[row], bf16 natural    (Q)
// EPI 1: bf16 natural                      (K)
// EPI 2: bf16 transposed V^T[b*768+o][n]   (V)
// EPI 3: += bias, f32 natural              (out proj)
template<int AMODE, int EPI>
__global__ __launch_bounds__(256, 2) void gemm_nt(
    const void* __restrict__ Ap, const unsigned short* __restrict__ Bw,
    void* __restrict__ Co, const float* __restrict__ uc, const float* __restrict__ bias) {
  constexpr int K = C_;
  __shared__ __align__(16) unsigned short Al[128 * 32];
  __shared__ __align__(16) unsigned short Bl[128 * 32];
  const int tid = threadIdx.x;
  const int w = tid >> 6, lane = tid & 63, quad = lane >> 4, id15 = lane & 15;
  const int wm = (w >> 1) << 6, wn = (w & 1) << 6;
  const int m0 = blockIdx.y << 7, n0 = blockIdx.x << 7;

  f32x4 acc[4][4] = {};

  for (int kt = 0; kt < K; kt += 32) {
    __syncthreads();
    if (AMODE == 0) {
      const float* A = (const float*)Ap;
#pragma unroll
      for (int s = 0; s < 4; ++s) {
        int cid = s * 256 + tid;                 // 1024 chunks of 4 elems
        int row = cid >> 3, col = (cid & 7) << 2;
        float4 v = *(const float4*)(A + (size_t)(m0 + row) * K + kt + col);
        ushort4 h;
        h.x = f2bs(v.x); h.y = f2bs(v.y); h.z = f2bs(v.z); h.w = f2bs(v.w);
        *(ushort4*)&Al[row * 32 + col] = h;
      }
    } else {
      const unsigned short* A = (const unsigned short*)Ap;
#pragma unroll
      for (int s = 0; s < 2; ++s) {
        int chunk = s * 256 + tid;               // 512 chunks of 8 elems
        int row = chunk >> 2, col = (chunk & 3) << 3;
        *(uint4*)&Al[chunk * 8] = *(const uint4*)(A + (size_t)(m0 + row) * K + kt + col);
      }
    }
#pragma unroll
    for (int s = 0; s < 2; ++s) {
      int chunk = s * 256 + tid;
      int row = chunk >> 2, col = (chunk & 3) << 3;
      *(uint4*)&Bl[chunk * 8] = *(const uint4*)(Bw + (size_t)(n0 + row) * K + kt + col);
    }
    __syncthreads();

    bf16x8 af[4], bfr[4];
#pragma unroll
    for (int i = 0; i < 4; ++i) {
      af[i]  = ldb8(&Al[(wm + i * 16 + id15) * 32 + quad * 8]);
      bfr[i] = ldb8(&Bl[(wn + i * 16 + id15) * 32 + quad * 8]);
    }
#pragma unroll
    for (int i = 0; i < 4; ++i)
#pragma unroll
      for (int j = 0; j < 4; ++j)
        acc[i][j] = mfma16(af[i], bfr[j], acc[i][j]);
  }

#pragma unroll
  for (int i = 0; i < 4; ++i) {
#pragma unroll
    for (int j = 0; j < 4; ++j) {
#pragma unroll
      for (int r = 0; r < 4; ++r) {
        int gm = m0 + wm + i * 16 + quad * 4 + r;   // global row (b*N + n)
        int gn = n0 + wn + j * 16 + id15;           // global out channel
        float v = acc[i][j][r];
        if (EPI == 0) {
          v *= 0.125f * uc[gm];
          ((unsigned short*)Co)[(size_t)gm * C_ + gn] = f2bs(v);
        } else if (EPI == 1) {
          ((unsigned short*)Co)[(size_t)gm * C_ + gn] = f2bs(v);
        } else if (EPI == 2) {
          int b = gm >> 11, n = gm & (N_ - 1);
          ((unsigned short*)Co)[(size_t)(b * C_ + gn) * N_ + n] = f2bs(v);
        } else {
          ((float*)Co)[(size_t)gm * C_ + gn] = v + bias[gn];
        }
      }
    }
  }
}

// ---------------- Flash attention ----------------
// Q: [B,N,C] bf16 (pre-scaled by SCALE*uc[row]); K: [B,N,C] bf16; Vt: [B*C, N] bf16 (V^T per head)
// O: [B,N,C] bf16. Grid: (N/128, B*H), block 256 (4 waves x 32 q-rows). K-chunks of 64.
__global__ __launch_bounds__(256, 2) void attn_kernel(
    const unsigned short* __restrict__ Q, const unsigned short* __restrict__ Kk,
    const unsigned short* __restrict__ Vt, unsigned short* __restrict__ O) {
  __shared__ __align__(16) unsigned short Kl[64 * 72];
  __shared__ __align__(16) unsigned short Vl[64 * 72];
  __shared__ __align__(16) unsigned short Pl[4][32 * 72];

  const int tid = threadIdx.x;
  const int w = tid >> 6, lane = tid & 63, quad = lane >> 4, id15 = lane & 15;
  const int bh = blockIdx.y;
  const int b = bh / H_, h = bh % H_;
  const int q0 = blockIdx.x * 128 + w * 32;

  // Q fragments: rg in {0,1} row groups of 16, kb in {0,1} K=32 halves of D=64
  bf16x8 qf[2][2];
#pragma unroll
  for (int rg = 0; rg < 2; ++rg)
#pragma unroll
    for (int kb = 0; kb < 2; ++kb)
      qf[rg][kb] = ldb8(Q + (size_t)(b * N_ + q0 + rg * 16 + id15) * C_ + h * 64 + kb * 32 + quad * 8);

  f32x4 oacc[2][4] = {};
  float mrow[2][4], lrow[2][4];
#pragma unroll
  for (int rg = 0; rg < 2; ++rg)
#pragma unroll
    for (int r = 0; r < 4; ++r) { mrow[rg][r] = -INFINITY; lrow[rg][r] = 0.f; }

  const size_t kbase = (size_t)(b * N_) * C_ + h * 64;
  const size_t vbase = (size_t)(b * C_ + h * 64) * N_;

  for (int kc = 0; kc < N_; kc += 64) {
    __syncthreads();
    // stage K chunk [64 keys x 64 d] and V^T chunk [64 d x 64 keys], padded stride 72
#pragma unroll
    for (int s = 0; s < 2; ++s) {
      int chunk = s * 256 + tid;                 // 512 chunks of 8 elems per tile
      int row = chunk >> 3, seg = (chunk & 7) << 3;
      *(uint4*)&Kl[row * 72 + seg] = *(const uint4*)(Kk + kbase + (size_t)(kc + row) * C_ + seg);
      *(uint4*)&Vl[row * 72 + seg] = *(const uint4*)(Vt + vbase + (size_t)row * N_ + kc + seg);
    }
    __syncthreads();

#pragma unroll
    for (int rg = 0; rg < 2; ++rg) {
      // S = Q Kt : 16 q-rows x 64 keys
      f32x4 s4[4];
#pragma unroll
      for (int cb = 0; cb < 4; ++cb) {
        f32x4 a = {};
#pragma unroll
        for (int kb = 0; kb < 2; ++kb) {
          bf16x8 kf = ldb8(&Kl[(cb * 16 + id15) * 72 + kb * 32 + quad * 8]);
          a = mfma16(qf[rg][kb], kf, a);
        }
        s4[cb] = a;
      }
      // online softmax for rows quad*4+r
      float al[4];
#pragma unroll
      for (int r = 0; r < 4; ++r) {
        float mx = fmaxf(fmaxf(s4[0][r], s4[1][r]), fmaxf(s4[2][r], s4[3][r]));
#pragma unroll
        for (int off = 1; off < 16; off <<= 1) mx = fmaxf(mx, __shfl_xor(mx, off));
        float mnew = fmaxf(mrow[rg][r], mx);
        float alpha = __expf(mrow[rg][r] - mnew);
        mrow[rg][r] = mnew;
        float rs = 0.f;
#pragma unroll
        for (int cb = 0; cb < 4; ++cb) {
          float p = __expf(s4[cb][r] - mnew);
          s4[cb][r] = p;
          rs += p;
        }
#pragma unroll
        for (int off = 1; off < 16; off <<= 1) rs += __shfl_xor(rs, off);
        lrow[rg][r] = lrow[rg][r] * alpha + rs;
        al[r] = alpha;
      }
      // P (C-layout) -> LDS (A-layout round trip), bf16
#pragma unroll
      for (int cb = 0; cb < 4; ++cb)
#pragma unroll
        for (int r = 0; r < 4; ++r)
          Pl[w][(rg * 16 + quad * 4 + r) * 72 + cb * 16 + id15] = f2bs(s4[cb][r]);
      // PV accumulate
      bf16x8 pf[2];
#pragma unroll
      for (int kb = 0; kb < 2; ++kb)
        pf[kb] = ldb8(&Pl[w][(rg * 16 + id15) * 72 + kb * 32 + quad * 8]);
#pragma unroll
      for (int db = 0; db < 4; ++db) {
        f32x4 o = oacc[rg][db];
#pragma unroll
        for (int r = 0; r < 4; ++r) o[r] *= al[r];
#pragma unroll
        for (int kb = 0; kb < 2; ++kb) {
          bf16x8 vf = ldb8(&Vl[(db * 16 + id15) * 72 + kb * 32 + quad * 8]);
          o = mfma16(pf[kb], vf, o);
        }
        oacc[rg][db] = o;
      }
    }
  }

  // write O (bf16, [B,N,C])
#pragma unroll
  for (int rg = 0; rg < 2; ++rg)
#pragma unroll
    for (int db = 0; db < 4; ++db)
#pragma unroll
      for (int r = 0; r < 4; ++r) {
        int n = q0 + rg * 16 + quad * 4 + r;
        float v = oacc[rg][db][r] / lrow[rg][r];
        O[(size_t)(b * N_ + n) * C_ + h * 64 + db * 16 + id15] = f2bs(v);
      }
}

extern "C" void kernel_launch(void* const* d_in, const int* in_sizes, int n_in,
                              void* d_out, int out_size, void* d_ws, size_t ws_size,
                              hipStream_t stream) {
  const float* x_q = (const float*)d_in[0];
  const float* x_k = (const float*)d_in[1];
  const float* x_v = (const float*)d_in[2];
  const float* x_u = (const float*)d_in[3];
  const float* Wq  = (const float*)d_in[4];
  const float* Wk  = (const float*)d_in[5];
  const float* Wv  = (const float*)d_in[6];
  const float* Wp  = (const float*)d_in[7];
  const float* bp  = (const float*)d_in[8];

  char* ws = (char*)d_ws;
  size_t off = 0;
  auto alloc = [&](size_t bytes) {
    char* p = ws + off;
    off += (bytes + 255) & ~(size_t)255;
    return p;
  };
  unsigned short* wq16 = (unsigned short*)alloc((size_t)C_ * C_ * 2);
  unsigned short* wk16 = (unsigned short*)alloc((size_t)C_ * C_ * 2);
  unsigned short* wv16 = (unsigned short*)alloc((size_t)C_ * C_ * 2);
  unsigned short* wp16 = (unsigned short*)alloc((size_t)C_ * C_ * 2);
  float*          ucp  = (float*)alloc((size_t)B_ * N_ * 4);
  unsigned short* q_s  = (unsigned short*)alloc((size_t)B_ * N_ * C_ * 2);
  unsigned short* k_s  = (unsigned short*)alloc((size_t)B_ * N_ * C_ * 2);
  unsigned short* vT   = (unsigned short*)alloc((size_t)B_ * N_ * C_ * 2);
  unsigned short* ao   = (unsigned short*)alloc((size_t)B_ * N_ * C_ * 2);

  convw_kernel<<<dim3(576, 4), 256, 0, stream>>>(Wq, Wk, Wv, Wp, wq16, wk16, wv16, wp16);
  uc_kernel<<<dim3(2048), 256, 0, stream>>>(x_u, ucp);
  gemm_nt<0, 0><<<dim3(6, 64), 256, 0, stream>>>(x_q, wq16, q_s, ucp, nullptr);
  gemm_nt<0, 1><<<dim3(6, 64), 256, 0, stream>>>(x_k, wk16, k_s, nullptr, nullptr);
  gemm_nt<0, 2><<<dim3(6, 64), 256, 0, stream>>>(x_v, wv16, vT, nullptr, nullptr);
  attn_kernel<<<dim3(16, 48), 256, 0, stream>>>(q_s, k_s, vT, ao);
  gemm_nt<1, 3><<<dim3(6, 64), 256, 0, stream>>>(ao, wp16, d_out, nullptr, bp);
}